// Round 16
// baseline (32.973 us; speedup 1.0000x reference)
//
#include <hip/hip_runtime.h>

#define BATCH 2048
#define IND   256
#define OUTD  256

typedef __attribute__((ext_vector_type(8))) short bf16x8;
typedef __attribute__((ext_vector_type(4))) float f32x4;

__device__ __forceinline__ ushort f2bf(float f) {
    uint u = __builtin_bit_cast(uint, f);
    u += 0x7fffu + ((u >> 16) & 1u);          // RNE
    return (ushort)(u >> 16);
}
__device__ __forceinline__ uint pack2(float lo, float hi) {
    return (uint)f2bf(lo) | ((uint)f2bf(hi) << 16);
}

// ---------------- ws layout (fallback A only) ----------------
#define BIASOFF (1u << 20)                 // W: [0, 1MB)
#define FOFF    ((1u << 20) + 4096)        // F: 8MB
#define WS_NEED ((size_t)FOFF + (size_t)IND * BATCH * 16)

#define LDSB2   131072                      // fallback kan_gemm: Wl [256][32]
#define LDSB4   163840                      // kan_reg: Wl 128KB + xs 32KB

// xs index: [i][row] f32 with bank skew (conflict-free hot-loop reads)
#define XIDX(i, row) ((i) * 32 + (((row) + 8 * ((i) & 3) + ((i) >> 2)) & 31))

// features for one x value: [silu, B0..B6] (c7 folded: B7 = 1 - sum -> bias)
__device__ __forceinline__ uint4 feat_pack(float xv) {
    const float u = (xv + 1.0f) * 2.5f;
    float cif = floorf(u);
    cif = fminf(fmaxf(cif, 0.0f), 4.0f);
    const int ci = (int)cif;
    const float f = u - cif, mf = 1.0f - f;
    const float f2 = f * f, f3 = f2 * f;
    const float k6 = 1.0f / 6.0f;
    const float w0 = mf * mf * mf * k6;
    const float w1 = (3.0f * f3 - 6.0f * f2 + 4.0f) * k6;
    const float w3 = f3 * k6;
    const float w2 = 1.0f - w0 - w1 - w3;
    const float sg = __fdividef(xv, 1.0f + __expf(-xv));
    const float B0 = (ci == 0) ? w0 : 0.f;
    const float B1 = (ci == 1) ? w0 : (ci == 0) ? w1 : 0.f;
    const float B2 = (ci == 2) ? w0 : (ci == 1) ? w1 : (ci == 0) ? w2 : 0.f;
    const float B3 = (ci == 3) ? w0 : (ci == 2) ? w1 : (ci == 1) ? w2 : (ci == 0) ? w3 : 0.f;
    const float B4 = (ci == 4) ? w0 : (ci == 3) ? w1 : (ci == 2) ? w2 : (ci == 1) ? w3 : 0.f;
    const float B5 = (ci == 4) ? w1 : (ci == 3) ? w2 : (ci == 2) ? w3 : 0.f;
    const float B6 = (ci == 4) ? w2 : (ci == 3) ? w3 : 0.f;
    uint4 v;
    v.x = pack2(sg, B0); v.y = pack2(B1, B2);
    v.z = pack2(B3, B4); v.w = pack2(B5, B6);
    return v;
}

__device__ __forceinline__ uint4 wpack(float m, float b, float sp,
                                       float4 c0, float4 c1) {
    const float wb = m * b, wsp = m * sp;
    const float c7 = c1.w;
    uint4 w;
    w.x = pack2(wb,                wsp * (c0.x - c7));
    w.y = pack2(wsp * (c0.y - c7), wsp * (c0.z - c7));
    w.z = pack2(wsp * (c0.w - c7), wsp * (c1.x - c7));
    w.w = pack2(wsp * (c1.y - c7), wsp * (c1.z - c7));
    return w;
}

// ============ PRIMARY: single-dispatch, A-fragments in-register ============
// 256 blocks x 512 threads (1/CU). o0 = (bid&7)*32 (XCD-pinned coef slice),
// block covers 2 m-tiles of 32 rows (Wl reused). LDS: Wl [256][32] packs
// (slot^=i&7) + xs [256 i][32 row] skewed f32. 8 waves = mq(2) x nh(2) x kq(2),
// wave owns 16x16 out tile, 32 barrier-free steps: feat_pack(xs read) -> A-frag
// in-register, ds_read_b128 B, 1 MFMA. Epilogue: 2-way kq-reduce + bias.
__global__ __launch_bounds__(512, 1) void kan_reg(
    const float* __restrict__ x, const float* __restrict__ coef,
    const float* __restrict__ sb, const float* __restrict__ ss,
    const float* __restrict__ mask, float* __restrict__ out)
{
    extern __shared__ char lds[];
    uint4* Wl = (uint4*)lds;               // [256][32], slot ^= i&7
    float* xs = (float*)(lds + 131072);    // [256][32] skewed (XIDX)

    const int tid = threadIdx.x;
    const int bid = blockIdx.x;
    const int o0 = (bid & 7) * 32;
    const int mg = bid >> 3;               // 0..31

    const int lane = tid & 63, wid = tid >> 6;
    const int kq = wid >> 2;               // 0..1
    const int mq = (wid >> 1) & 1;
    const int nh = wid & 1;
    const int r = lane & 15, g = lane >> 4;

    // ---- prologue: Wl from coef (coalesced, XCD-local) + bias partials ----
    {
        float c7s = 0.f;
        const int po = tid & 31, pig = tid >> 5;     // pig 0..15
#pragma unroll 4
        for (int p = 0; p < 16; ++p) {
            const int i  = p * 16 + pig;
            const int io = i * OUTD + o0 + po;
            const float4* cp = reinterpret_cast<const float4*>(coef + (size_t)io * 8);
            const float4 c0 = cp[0], c1 = cp[1];
            const float m = mask[io];
            c7s += m * ss[io] * c1.w;
            Wl[i * 32 + (po ^ (i & 7))] = wpack(m, sb[io], ss[io], c0, c1);
        }
        xs[pig * 32 + po] = c7s;                     // part[16][32]
    }
    __syncthreads();
    float bv = 0.f;
    {
        const int myo = nh * 16 + r;
#pragma unroll
        for (int k2 = 0; k2 < 16; ++k2) bv += xs[k2 * 32 + myo];
    }

    const int myrow = mq * 16 + r;
    const int bcol  = nh * 16 + r;

    for (int mt = 0; mt < 2; ++mt) {
        const int b0m = (mg * 2 + mt) * 32;
        __syncthreads();                             // bv reads / prev epilogue done

        // ---- stage xs (coalesced global, skewed scalar LDS writes) ----
        {
            const int row = tid >> 4, c4 = (tid & 15) * 4;
#pragma unroll
            for (int q = 0; q < 4; ++q) {
                const int ii = c4 + q * 64;
                const float4 v = *reinterpret_cast<const float4*>(
                    x + (size_t)(b0m + row) * IND + ii);
                xs[XIDX(ii + 0, row)] = v.x;
                xs[XIDX(ii + 1, row)] = v.y;
                xs[XIDX(ii + 2, row)] = v.z;
                xs[XIDX(ii + 3, row)] = v.w;
            }
        }
        __syncthreads();

        // ---- barrier-free K-loop: 32 steps ----
        f32x4 acc = {0.f, 0.f, 0.f, 0.f};
#pragma unroll 4
        for (int t = 0; t < 32; ++t) {
            const int i = kq * 128 + t * 4 + g;      // i&3 == g
            const float xv = xs[XIDX(i, myrow)];
            const bf16x8 a = __builtin_bit_cast(bf16x8, feat_pack(xv));
            const bf16x8 b = __builtin_bit_cast(bf16x8, Wl[i * 32 + (bcol ^ (i & 7))]);
            acc = __builtin_amdgcn_mfma_f32_16x16x32_bf16(a, b, acc, 0, 0, 0);
        }

        // ---- epilogue: 2-way kq-reduce (reuse xs), bias, store ----
        __syncthreads();                             // xs reads done
        if (kq == 1)
            *reinterpret_cast<f32x4*>(xs + (mq * 2 + nh) * 1024 + lane * 4) = acc;
        __syncthreads();
        if (kq == 0) {
            const f32x4 v = *reinterpret_cast<const f32x4*>(
                xs + (mq * 2 + nh) * 1024 + lane * 4);
            acc.x += v.x; acc.y += v.y; acc.z += v.z; acc.w += v.w;
            const int col  = o0 + bcol;
            const int row0 = b0m + mq * 16 + g * 4;
#pragma unroll
            for (int e = 0; e < 4; ++e)
                out[(size_t)(row0 + e) * OUTD + col] = acc[e] + bv;
        }
    }
}

// ============ fallback A: R14 two-kernel path (proven 17.4µs) ============
__global__ __launch_bounds__(256) void kan_prep(
    const float* __restrict__ x, const float* __restrict__ coef,
    const float* __restrict__ sb, const float* __restrict__ ss,
    const float* __restrict__ mask,
    uint4* __restrict__ W, float* __restrict__ bias, uint4* __restrict__ F)
{
    const int bid = blockIdx.x, tid = threadIdx.x;
    __shared__ float xt[4 * 260];
    __shared__ float part[32][8];

    const int b0 = (bid & 7) * 256 + (bid >> 3) * 4;
    {
        const int row = tid >> 6, c4 = (tid & 63) * 4;
        const float4 v = *reinterpret_cast<const float4*>(
            x + (size_t)(b0 + row) * IND + c4);
        xt[row * 260 + c4 + 0] = v.x;
        xt[row * 260 + c4 + 1] = v.y;
        xt[row * 260 + c4 + 2] = v.z;
        xt[row * 260 + c4 + 3] = v.w;
    }
    if (tid < 128) {
        const int i = bid >> 1, o = (bid & 1) * 128 + tid;
        const int io = i * OUTD + o;
        const float4* cp = reinterpret_cast<const float4*>(coef + (size_t)io * 8);
        W[io] = wpack(mask[io], sb[io], ss[io], cp[0], cp[1]);
    }
    __syncthreads();
#pragma unroll
    for (int p = 0; p < 4; ++p) {
        const int q = p * 256 + tid;
        const int i = q >> 2, b = q & 3;
        F[(size_t)i * BATCH + b0 + b] = feat_pack(xt[b * 260 + i]);
    }
    if (bid >= 480) {
        const int o0 = (bid - 480) * 8;
        const int ol = tid & 7, ig = tid >> 3;
        float s = 0.f;
#pragma unroll
        for (int ii = 0; ii < 8; ++ii) {
            const int i = ig * 8 + ii;
            const int io = i * OUTD + o0 + ol;
            s += mask[io] * ss[io] * coef[(size_t)io * 8 + 7];
        }
        part[ig][ol] = s;
        __syncthreads();
        if (tid < 8) {
            float acc = 0.f;
#pragma unroll
            for (int g2 = 0; g2 < 32; ++g2) acc += part[g2][tid];
            bias[o0 + tid] = acc;
        }
    }
}

__global__ __launch_bounds__(512, 1) void kan_gemm(
    const uint4* __restrict__ F, const uint4* __restrict__ W,
    const float* __restrict__ bias, float* __restrict__ out)
{
    extern __shared__ uint4 Wl[];

    const int tid  = threadIdx.x;
    const int lane = tid & 63, wid = tid >> 6;
    const int mh = wid & 1, kq = wid >> 1;
    const int r = lane & 15, g = lane >> 4;
    const int bid = blockIdx.x;
    const int xcd = bid & 7;
    const int b0 = xcd * 256 + ((bid >> 3) & 3) * 64;
    const int o0 = (bid >> 5) * 32;

#pragma unroll
    for (int p = 0; p < 16; ++p) {
        const int s = p * 512 + tid;
        const int i = s >> 5, o = s & 31;
        Wl[i * 32 + (o ^ (i & 7))] = W[(size_t)i * OUTD + o0 + o];
    }
    __syncthreads();

    const int rowA0 = b0 + mh * 32 + r;
    f32x4 acc[2][2] = {};

    const uint4* pA = F + (size_t)(kq * 64 + g) * BATCH + rowA0;
    bf16x8 aC0 = *reinterpret_cast<const bf16x8*>(pA);
    bf16x8 aC1 = *reinterpret_cast<const bf16x8*>(pA + 16);
    bf16x8 aN0, aN1;

#pragma unroll
    for (int t = 0; t < 16; ++t) {
        const int i = kq * 64 + t * 4 + g;
        if (t < 15) {
            const uint4* pn = F + (size_t)(i + 4) * BATCH + rowA0;
            aN0 = *reinterpret_cast<const bf16x8*>(pn);
            aN1 = *reinterpret_cast<const bf16x8*>(pn + 16);
        }
        const bf16x8 bb0 = __builtin_bit_cast(bf16x8, Wl[i * 32 + (r ^ (i & 7))]);
        const bf16x8 bb1 = __builtin_bit_cast(bf16x8, Wl[i * 32 + ((16 + r) ^ (i & 7))]);

        acc[0][0] = __builtin_amdgcn_mfma_f32_16x16x32_bf16(aC0, bb0, acc[0][0], 0, 0, 0);
        acc[0][1] = __builtin_amdgcn_mfma_f32_16x16x32_bf16(aC0, bb1, acc[0][1], 0, 0, 0);
        acc[1][0] = __builtin_amdgcn_mfma_f32_16x16x32_bf16(aC1, bb0, acc[1][0], 0, 0, 0);
        acc[1][1] = __builtin_amdgcn_mfma_f32_16x16x32_bf16(aC1, bb1, acc[1][1], 0, 0, 0);

        aC0 = aN0; aC1 = aN1;
    }

    __syncthreads();
    float* red = (float*)Wl;
    if (kq > 0) {
        float* dst = red + (size_t)(mh * 3 + kq - 1) * 1024;
#pragma unroll
        for (int mf = 0; mf < 2; ++mf)
#pragma unroll
            for (int nf = 0; nf < 2; ++nf)
                *reinterpret_cast<f32x4*>(dst + (mf * 2 + nf) * 256 + lane * 4) = acc[mf][nf];
    }
    __syncthreads();
    if (kq == 0) {
#pragma unroll
        for (int mf = 0; mf < 2; ++mf)
#pragma unroll
            for (int nf = 0; nf < 2; ++nf) {
                f32x4 s = acc[mf][nf];
                const int sl = (mf * 2 + nf) * 256 + lane * 4;
#pragma unroll
                for (int kk = 0; kk < 3; ++kk) {
                    const f32x4 v = *reinterpret_cast<const f32x4*>(
                        red + (size_t)(mh * 3 + kk) * 1024 + sl);
                    s.x += v.x; s.y += v.y; s.z += v.z; s.w += v.w;
                }
                const int col  = o0 + nf * 16 + r;
                const int row0 = b0 + mh * 32 + mf * 16 + g * 4;
                const float bvv = bias[col];
#pragma unroll
                for (int e = 0; e < 4; ++e)
                    out[(size_t)(row0 + e) * OUTD + col] = s[e] + bvv;
            }
    }
}

// ============ fallback B: self-contained fused (no ws, static LDS) ============
#define KPI  16
#define IPC  8
#define KC   (IPC * KPI)

__global__ __launch_bounds__(256, 2) void kan_mfma(
    const float* __restrict__ x, const float* __restrict__ coef,
    const float* __restrict__ scale_base, const float* __restrict__ scale_sp,
    const float* __restrict__ mask, float* __restrict__ out)
{
    const int tid = threadIdx.x;
    const int b0 = blockIdx.x * 32, o0 = blockIdx.y * 32;
    __shared__ uint Fa[32 * KC / 2];
    __shared__ uint Wt2[32 * KC / 2];
    for (int j = tid; j < 32 * KC / 2; j += 256) { Fa[j] = 0u; Wt2[j] = 0u; }
    const int lane = tid & 63, wid = tid >> 6;
    const int wmv = (wid >> 1) * 16, wnv = (wid & 1) * 16;
    f32x4 acc = {0.f, 0.f, 0.f, 0.f};
    const int fb = tid & 31, il = tid >> 5;
    for (int ic = 0; ic < IND / IPC; ++ic) {
        const int i = ic * IPC + il;
        __syncthreads();
        {
            const uint4 fp = feat_pack(x[(b0 + fb) * IND + i]);
            const int base = fb * (KC / 2) + il * (KPI / 2);
            const int sw = (fb & 7) << 2;
            Fa[(base + 0) ^ sw] = fp.x; Fa[(base + 1) ^ sw] = fp.y;
            Fa[(base + 2) ^ sw] = fp.z; Fa[(base + 3) ^ sw] = fp.w;
            ((ushort*)Fa)[2 * ((base + 4) ^ sw)] = 0;
        }
        {
            const int io = i * OUTD + o0 + fb;
            const float4* cp = reinterpret_cast<const float4*>(coef + (size_t)io * 8);
            const uint4 w = wpack(mask[io], scale_base[io], scale_sp[io], cp[0], cp[1]);
            const int base = fb * (KC / 2) + il * (KPI / 2);
            const int sw = (fb & 7) << 2;
            Wt2[(base + 0) ^ sw] = w.x;
            Wt2[(base + 1) ^ sw] = w.y;
            Wt2[(base + 2) ^ sw] = w.z;
            Wt2[(base + 3) ^ sw] = w.w;
            ((ushort*)Wt2)[2 * ((base + 4) ^ sw)] = 0;
        }
        __syncthreads();
        {
            const ushort* fs = (const ushort*)Fa;
            const ushort* wsd = (const ushort*)Wt2;
            const int ar = wmv + (lane & 15), br = wnv + (lane & 15);
            const int kg = (lane >> 4) * 8;
#pragma unroll
            for (int ksi = 0; ksi < 4; ++ksi) {
                const int ka = ksi * 32 + kg;
                const int ia = (ar * KC + ka) ^ ((ar & 7) << 3);
                const int ib = (br * KC + ka) ^ ((br & 7) << 3);
                bf16x8 a = *reinterpret_cast<const bf16x8*>(fs + ia);
                bf16x8 b = *reinterpret_cast<const bf16x8*>(wsd + ib);
                acc = __builtin_amdgcn_mfma_f32_16x16x32_bf16(a, b, acc, 0, 0, 0);
            }
        }
    }
    const int col = o0 + wnv + (lane & 15);
    const int row0 = b0 + wmv + ((lane >> 4) << 2);
    float bv = 0.f;
    for (int i = 0; i < IND; ++i) {
        const int io = i * OUTD + col;
        bv += mask[io] * scale_sp[io] * coef[(size_t)io * 8 + 7];
    }
#pragma unroll
    for (int rr = 0; rr < 4; ++rr)
        out[(size_t)(row0 + rr) * OUTD + col] = acc[rr] + bv;
}

extern "C" void kernel_launch(void* const* d_in, const int* in_sizes, int n_in,
                              void* d_out, int out_size, void* d_ws, size_t ws_size,
                              hipStream_t stream) {
    const float* x          = (const float*)d_in[0];
    const float* coef       = (const float*)d_in[2];
    const float* scale_base = (const float*)d_in[3];
    const float* scale_sp   = (const float*)d_in[4];
    const float* mask       = (const float*)d_in[5];
    float* out = (float*)d_out;

    hipError_t e1 = hipFuncSetAttribute(
        (const void*)kan_reg, hipFuncAttributeMaxDynamicSharedMemorySize, LDSB4);
    if (e1 == hipSuccess) {
        kan_reg<<<256, 512, LDSB4, stream>>>(x, coef, scale_base, scale_sp, mask, out);
        return;
    }

    hipError_t e2 = hipFuncSetAttribute(
        (const void*)kan_gemm, hipFuncAttributeMaxDynamicSharedMemorySize, LDSB2);
    if (e2 == hipSuccess && ws_size >= WS_NEED) {
        uint4* W    = (uint4*)d_ws;
        float* bias = (float*)((char*)d_ws + BIASOFF);
        uint4* F    = (uint4*)((char*)d_ws + FOFF);
        kan_prep<<<512, 256, 0, stream>>>(x, coef, scale_base, scale_sp, mask, W, bias, F);
        kan_gemm<<<256, 512, LDSB2, stream>>>(F, W, bias, out);
    } else {
        kan_mfma<<<dim3(BATCH / 32, OUTD / 32), 256, 0, stream>>>(
            x, coef, scale_base, scale_sp, mask, out);
    }
}

// Round 17
// 17.178 us; speedup vs baseline: 1.9195x; 1.9195x over previous
//
#include <hip/hip_runtime.h>

#define BATCH 2048
#define IND   256
#define OUTD  256

typedef __attribute__((ext_vector_type(8))) short bf16x8;
typedef __attribute__((ext_vector_type(4))) float f32x4;

#define AS1 __attribute__((address_space(1)))
#define AS3 __attribute__((address_space(3)))

__device__ __forceinline__ ushort f2bf(float f) {
    uint u = __builtin_bit_cast(uint, f);
    u += 0x7fffu + ((u >> 16) & 1u);          // RNE
    return (ushort)(u >> 16);
}
__device__ __forceinline__ uint pack2(float lo, float hi) {
    return (uint)f2bf(lo) | ((uint)f2bf(hi) << 16);
}

// ---------------- ws layout ----------------
#define BIASOFF (1u << 20)                 // W: [0, 1MB)
#define FOFF    ((1u << 20) + 4096)        // F: 8MB
#define WS_NEED ((size_t)FOFF + (size_t)IND * BATCH * 16)

#define LDSB2   131072                      // kan_gemm: Wl [256][32] uint4

// features for one x value: [silu, B0..B6] (c7 folded: B7 = 1 - sum -> bias)
__device__ __forceinline__ uint4 feat_pack(float xv) {
    const float u = (xv + 1.0f) * 2.5f;
    float cif = floorf(u);
    cif = fminf(fmaxf(cif, 0.0f), 4.0f);
    const int ci = (int)cif;
    const float f = u - cif, mf = 1.0f - f;
    const float f2 = f * f, f3 = f2 * f;
    const float k6 = 1.0f / 6.0f;
    const float w0 = mf * mf * mf * k6;
    const float w1 = (3.0f * f3 - 6.0f * f2 + 4.0f) * k6;
    const float w3 = f3 * k6;
    const float w2 = 1.0f - w0 - w1 - w3;
    const float sg = __fdividef(xv, 1.0f + __expf(-xv));
    const float B0 = (ci == 0) ? w0 : 0.f;
    const float B1 = (ci == 1) ? w0 : (ci == 0) ? w1 : 0.f;
    const float B2 = (ci == 2) ? w0 : (ci == 1) ? w1 : (ci == 0) ? w2 : 0.f;
    const float B3 = (ci == 3) ? w0 : (ci == 2) ? w1 : (ci == 1) ? w2 : (ci == 0) ? w3 : 0.f;
    const float B4 = (ci == 4) ? w0 : (ci == 3) ? w1 : (ci == 2) ? w2 : (ci == 1) ? w3 : 0.f;
    const float B5 = (ci == 4) ? w1 : (ci == 3) ? w2 : (ci == 2) ? w3 : 0.f;
    const float B6 = (ci == 4) ? w2 : (ci == 3) ? w3 : 0.f;
    uint4 v;
    v.x = pack2(sg, B0); v.y = pack2(B1, B2);
    v.z = pack2(B3, B4); v.w = pack2(B5, B6);
    return v;
}

__device__ __forceinline__ uint4 wpack(float m, float b, float sp,
                                       float4 c0, float4 c1) {
    const float wb = m * b, wsp = m * sp;
    const float c7 = c1.w;
    uint4 w;
    w.x = pack2(wb,                wsp * (c0.x - c7));
    w.y = pack2(wsp * (c0.y - c7), wsp * (c0.z - c7));
    w.z = pack2(wsp * (c0.w - c7), wsp * (c1.x - c7));
    w.w = pack2(wsp * (c1.y - c7), wsp * (c1.z - c7));
    return w;
}

// ============ kernel 1: prep (R14 verbatim — proven) ============
__global__ __launch_bounds__(256) void kan_prep(
    const float* __restrict__ x, const float* __restrict__ coef,
    const float* __restrict__ sb, const float* __restrict__ ss,
    const float* __restrict__ mask,
    uint4* __restrict__ W, float* __restrict__ bias, uint4* __restrict__ F)
{
    const int bid = blockIdx.x, tid = threadIdx.x;
    __shared__ float xt[4 * 260];
    __shared__ float part[32][8];

    const int b0 = (bid & 7) * 256 + (bid >> 3) * 4;
    {
        const int row = tid >> 6, c4 = (tid & 63) * 4;
        const float4 v = *reinterpret_cast<const float4*>(
            x + (size_t)(b0 + row) * IND + c4);
        xt[row * 260 + c4 + 0] = v.x;
        xt[row * 260 + c4 + 1] = v.y;
        xt[row * 260 + c4 + 2] = v.z;
        xt[row * 260 + c4 + 3] = v.w;
    }
    if (tid < 128) {
        const int i = bid >> 1, o = (bid & 1) * 128 + tid;
        const int io = i * OUTD + o;
        const float4* cp = reinterpret_cast<const float4*>(coef + (size_t)io * 8);
        W[io] = wpack(mask[io], sb[io], ss[io], cp[0], cp[1]);
    }
    __syncthreads();
#pragma unroll
    for (int p = 0; p < 4; ++p) {
        const int q = p * 256 + tid;
        const int i = q >> 2, b = q & 3;
        F[(size_t)i * BATCH + b0 + b] = feat_pack(xt[b * 260 + i]);
    }
    if (bid >= 480) {
        const int o0 = (bid - 480) * 8;
        const int ol = tid & 7, ig = tid >> 3;
        float s = 0.f;
#pragma unroll
        for (int ii = 0; ii < 8; ++ii) {
            const int i = ig * 8 + ii;
            const int io = i * OUTD + o0 + ol;
            s += mask[io] * ss[io] * coef[(size_t)io * 8 + 7];
        }
        part[ig][ol] = s;
        __syncthreads();
        if (tid < 8) {
            float acc = 0.f;
#pragma unroll
            for (int g2 = 0; g2 < 32; ++g2) acc += part[g2][tid];
            bias[o0 + tid] = acc;
        }
    }
}

// ============ kernel 2: whole-K B-in-LDS GEMM + async fill + depth-4 A ============
// 256 blocks x 512 threads (1/CU). Block tile 64M x 32N, full K.
// xcd = bid&7: b0 = xcd*256 + ((bid>>3)&3)*64 (XCD-local F slice), o0 = (bid>>5)*32.
// Prologue: async global_load_lds fill of Wl (linear LDS dest = uniform+lane*16,
//   swizzle moved to the per-lane GLOBAL source address — rule-21 compliant).
// K-loop (no barriers): 8 waves = kq(4) x mh(2), wave tile 32x32 = 2x2 frags;
//   depth-4 A prefetch (8 loads in flight), 2 conflict-free ds_read_b128, 4 MFMA/step.
// Epilogue: 4-way kq-reduce (reuses LDS) + bias + store.
__global__ __launch_bounds__(512, 1) void kan_gemm(
    const uint4* __restrict__ F, const uint4* __restrict__ W,
    const float* __restrict__ bias, float* __restrict__ out)
{
    extern __shared__ uint4 Wl[];                     // [256][32], slot ^= i&7

    const int tid  = threadIdx.x;
    const int lane = tid & 63, wid = tid >> 6;
    const int mh = wid & 1, kq = wid >> 1;            // kq 0..3
    const int r = lane & 15, g = lane >> 4;
    const int bid = blockIdx.x;
    const int xcd = bid & 7;
    const int b0 = xcd * 256 + ((bid >> 3) & 3) * 64; // XCD-local m-tile
    const int o0 = (bid >> 5) * 32;

    // ---- prologue: async Wl fill; LDS dest linear per-lane, source pre-swizzled ----
    // slot s holds W for (i = s>>5, o_logical = (s&31) ^ (i&7)).
#pragma unroll
    for (int p = 0; p < 16; ++p) {
        const int s = p * 512 + tid;                  // dest slot (linear in tid ✓)
        const int i = s >> 5;
        const int o = (s & 31) ^ (i & 7);             // pre-swizzled source column
        __builtin_amdgcn_global_load_lds(
            (const AS1 uint*)(W + (size_t)i * OUTD + o0 + o),
            (AS3 uint*)(Wl + s), 16, 0, 0);
    }
    __syncthreads();                                  // drains vmcnt + barrier

    // ---- K-loop: 16 steps, depth-4 A prefetch, B from LDS ----
    const int rowA0 = b0 + mh * 32 + r;
    f32x4 acc[2][2] = {};
    bf16x8 a0_0, a1_0, a0_1, a1_1, a0_2, a1_2, a0_3, a1_3;

#define LDA_(s, t)                                                                      \
    {                                                                                   \
        const uint4* pA = F + (size_t)(kq * 64 + (t) * 4 + g) * BATCH + rowA0;          \
        a0_##s = *reinterpret_cast<const bf16x8*>(pA);                                  \
        a1_##s = *reinterpret_cast<const bf16x8*>(pA + 16);                             \
    }
#define MM_(s, t)                                                                       \
    {                                                                                   \
        const int i = kq * 64 + (t) * 4 + g;                                            \
        const bf16x8 bb0 = __builtin_bit_cast(bf16x8, Wl[i * 32 + (r ^ (i & 7))]);      \
        const bf16x8 bb1 = __builtin_bit_cast(bf16x8, Wl[i * 32 + ((16 + r) ^ (i & 7))]); \
        acc[0][0] = __builtin_amdgcn_mfma_f32_16x16x32_bf16(a0_##s, bb0, acc[0][0], 0, 0, 0); \
        acc[0][1] = __builtin_amdgcn_mfma_f32_16x16x32_bf16(a0_##s, bb1, acc[0][1], 0, 0, 0); \
        acc[1][0] = __builtin_amdgcn_mfma_f32_16x16x32_bf16(a1_##s, bb0, acc[1][0], 0, 0, 0); \
        acc[1][1] = __builtin_amdgcn_mfma_f32_16x16x32_bf16(a1_##s, bb1, acc[1][1], 0, 0, 0); \
    }

    LDA_(0, 0)  LDA_(1, 1)  LDA_(2, 2)  LDA_(3, 3)
    MM_(0, 0)  LDA_(0, 4)   MM_(1, 1)  LDA_(1, 5)
    MM_(2, 2)  LDA_(2, 6)   MM_(3, 3)  LDA_(3, 7)
    MM_(0, 4)  LDA_(0, 8)   MM_(1, 5)  LDA_(1, 9)
    MM_(2, 6)  LDA_(2, 10)  MM_(3, 7)  LDA_(3, 11)
    MM_(0, 8)  LDA_(0, 12)  MM_(1, 9)  LDA_(1, 13)
    MM_(2, 10) LDA_(2, 14)  MM_(3, 11) LDA_(3, 15)
    MM_(0, 12) MM_(1, 13)   MM_(2, 14) MM_(3, 15)
#undef LDA_
#undef MM_

    // ---- epilogue: 4-way kq-reduce per mh (reuse Wl), add bias, store ----
    __syncthreads();
    float* red = (float*)Wl;                          // [2][3][4][256] = 24KB
    if (kq > 0) {
        float* dst = red + (size_t)(mh * 3 + kq - 1) * 1024;
#pragma unroll
        for (int mf = 0; mf < 2; ++mf)
#pragma unroll
            for (int nf = 0; nf < 2; ++nf)
                *reinterpret_cast<f32x4*>(dst + (mf * 2 + nf) * 256 + lane * 4) = acc[mf][nf];
    }
    __syncthreads();
    if (kq == 0) {
#pragma unroll
        for (int mf = 0; mf < 2; ++mf)
#pragma unroll
            for (int nf = 0; nf < 2; ++nf) {
                f32x4 s = acc[mf][nf];
                const int sl = (mf * 2 + nf) * 256 + lane * 4;
#pragma unroll
                for (int kk = 0; kk < 3; ++kk) {
                    const f32x4 v = *reinterpret_cast<const f32x4*>(
                        red + (size_t)(mh * 3 + kk) * 1024 + sl);
                    s.x += v.x; s.y += v.y; s.z += v.z; s.w += v.w;
                }
                const int col  = o0 + nf * 16 + r;
                const int row0 = b0 + mh * 32 + mf * 16 + g * 4;
                const float bv = bias[col];
#pragma unroll
                for (int e = 0; e < 4; ++e)
                    out[(size_t)(row0 + e) * OUTD + col] = s[e] + bv;
            }
    }
}

// ============ fallback: self-contained fused (no ws, static LDS) ============
#define KPI  16
#define IPC  8
#define KC   (IPC * KPI)

__global__ __launch_bounds__(256, 2) void kan_mfma(
    const float* __restrict__ x, const float* __restrict__ coef,
    const float* __restrict__ scale_base, const float* __restrict__ scale_sp,
    const float* __restrict__ mask, float* __restrict__ out)
{
    const int tid = threadIdx.x;
    const int b0 = blockIdx.x * 32, o0 = blockIdx.y * 32;
    __shared__ uint Fa[32 * KC / 2];
    __shared__ uint Wt2[32 * KC / 2];
    for (int j = tid; j < 32 * KC / 2; j += 256) { Fa[j] = 0u; Wt2[j] = 0u; }
    const int lane = tid & 63, wid = tid >> 6;
    const int wmv = (wid >> 1) * 16, wnv = (wid & 1) * 16;
    f32x4 acc = {0.f, 0.f, 0.f, 0.f};
    const int fb = tid & 31, il = tid >> 5;
    for (int ic = 0; ic < IND / IPC; ++ic) {
        const int i = ic * IPC + il;
        __syncthreads();
        {
            const uint4 fp = feat_pack(x[(b0 + fb) * IND + i]);
            const int base = fb * (KC / 2) + il * (KPI / 2);
            const int sw = (fb & 7) << 2;
            Fa[(base + 0) ^ sw] = fp.x; Fa[(base + 1) ^ sw] = fp.y;
            Fa[(base + 2) ^ sw] = fp.z; Fa[(base + 3) ^ sw] = fp.w;
            ((ushort*)Fa)[2 * ((base + 4) ^ sw)] = 0;
        }
        {
            const int io = i * OUTD + o0 + fb;
            const float4* cp = reinterpret_cast<const float4*>(coef + (size_t)io * 8);
            const uint4 w = wpack(mask[io], scale_base[io], scale_sp[io], cp[0], cp[1]);
            const int base = fb * (KC / 2) + il * (KPI / 2);
            const int sw = (fb & 7) << 2;
            Wt2[(base + 0) ^ sw] = w.x;
            Wt2[(base + 1) ^ sw] = w.y;
            Wt2[(base + 2) ^ sw] = w.z;
            Wt2[(base + 3) ^ sw] = w.w;
            ((ushort*)Wt2)[2 * ((base + 4) ^ sw)] = 0;
        }
        __syncthreads();
        {
            const ushort* fs = (const ushort*)Fa;
            const ushort* wsd = (const ushort*)Wt2;
            const int ar = wmv + (lane & 15), br = wnv + (lane & 15);
            const int kg = (lane >> 4) * 8;
#pragma unroll
            for (int ksi = 0; ksi < 4; ++ksi) {
                const int ka = ksi * 32 + kg;
                const int ia = (ar * KC + ka) ^ ((ar & 7) << 3);
                const int ib = (br * KC + ka) ^ ((br & 7) << 3);
                bf16x8 a = *reinterpret_cast<const bf16x8*>(fs + ia);
                bf16x8 b = *reinterpret_cast<const bf16x8*>(wsd + ib);
                acc = __builtin_amdgcn_mfma_f32_16x16x32_bf16(a, b, acc, 0, 0, 0);
            }
        }
    }
    const int col = o0 + wnv + (lane & 15);
    const int row0 = b0 + wmv + ((lane >> 4) << 2);
    float bv = 0.f;
    for (int i = 0; i < IND; ++i) {
        const int io = i * OUTD + col;
        bv += mask[io] * scale_sp[io] * coef[(size_t)io * 8 + 7];
    }
#pragma unroll
    for (int rr = 0; rr < 4; ++rr)
        out[(size_t)(row0 + rr) * OUTD + col] = acc[rr] + bv;
}

extern "C" void kernel_launch(void* const* d_in, const int* in_sizes, int n_in,
                              void* d_out, int out_size, void* d_ws, size_t ws_size,
                              hipStream_t stream) {
    const float* x          = (const float*)d_in[0];
    const float* coef       = (const float*)d_in[2];
    const float* scale_base = (const float*)d_in[3];
    const float* scale_sp   = (const float*)d_in[4];
    const float* mask       = (const float*)d_in[5];
    float* out = (float*)d_out;

    hipError_t e = hipFuncSetAttribute(
        (const void*)kan_gemm, hipFuncAttributeMaxDynamicSharedMemorySize, LDSB2);

    if (e == hipSuccess && ws_size >= WS_NEED) {
        uint4* W    = (uint4*)d_ws;
        float* bias = (float*)((char*)d_ws + BIASOFF);
        uint4* F    = (uint4*)((char*)d_ws + FOFF);
        kan_prep<<<512, 256, 0, stream>>>(x, coef, scale_base, scale_sp, mask, W, bias, F);
        kan_gemm<<<256, 512, LDSB2, stream>>>(F, W, bias, out);
    } else {
        kan_mfma<<<dim3(BATCH / 32, OUTD / 32), 256, 0, stream>>>(
            x, coef, scale_base, scale_sp, mask, out);
    }
}